// Round 1
// 186.312 us; speedup vs baseline: 1.0033x; 1.0033x over previous
//
#include <hip/hip_runtime.h>
#include <hip/hip_bf16.h>
#include <math.h>

#define DMODEL 1024
#define NHEAD  16
#define DHEAD  64
#define BATCH  2
#define SEQ    2048
#define MROWS  (BATCH * SEQ)   // 4096

typedef __attribute__((ext_vector_type(8))) __bf16 bf16x8;
typedef __attribute__((ext_vector_type(4))) float  f32x4;

// async global->LDS, 16 B per lane. LDS dest must be wave-uniform base + lane*16.
__device__ __forceinline__ void load16_lds(const ushort* g, ushort* l) {
    __builtin_amdgcn_global_load_lds(
        (const __attribute__((address_space(1))) unsigned int*)g,
        (__attribute__((address_space(3))) unsigned int*)l, 16, 0, 0);
}

__device__ __forceinline__ ushort bf16u(float v) {
    __hip_bfloat16 h = __float2bfloat16(v);
    return *reinterpret_cast<ushort*>(&h);
}

// ---------------------------------------------------------------------------
// fp32 -> bf16 casts
// ---------------------------------------------------------------------------
__global__ __launch_bounds__(256)
void cast_f32_bf16(const float* __restrict__ s, ushort* __restrict__ d, int n) {
    const int i = (blockIdx.x * 256 + threadIdx.x) * 8;
    if (i >= n) return;
    const f32x4 a = *reinterpret_cast<const f32x4*>(s + i);
    const f32x4 b = *reinterpret_cast<const f32x4*>(s + i + 4);
    bf16x8 o;
    #pragma unroll
    for (int j = 0; j < 4; j++) { o[j] = (__bf16)a[j]; o[4 + j] = (__bf16)b[j]; }
    *reinterpret_cast<bf16x8*>(d + i) = o;
}

__global__ __launch_bounds__(256)
void cast_w4(const float* __restrict__ w0, const float* __restrict__ w1,
             const float* __restrict__ w2, const float* __restrict__ w3,
             ushort* __restrict__ dst) {
    const float* src = (blockIdx.y == 0) ? w0 : (blockIdx.y == 1) ? w1
                     : (blockIdx.y == 2) ? w2 : w3;
    const int i = (blockIdx.x * 256 + threadIdx.x) * 8;
    const f32x4 a = *reinterpret_cast<const f32x4*>(src + i);
    const f32x4 b = *reinterpret_cast<const f32x4*>(src + i + 4);
    bf16x8 o;
    #pragma unroll
    for (int j = 0; j < 4; j++) { o[j] = (__bf16)a[j]; o[4 + j] = (__bf16)b[j]; }
    *reinterpret_cast<bf16x8*>(dst + (size_t)blockIdx.y * DMODEL * DMODEL + i) = o;
}

// ---------------------------------------------------------------------------
// RoPE cos/sin table: tab[s*32+i] = (cos, sin) of pos[s] * 10000^(-2i/64).
// ---------------------------------------------------------------------------
__global__ __launch_bounds__(256)
void rope_tab(const int* __restrict__ pos, float2* __restrict__ tab) {
    const int idx = blockIdx.x * 256 + threadIdx.x;   // 0..65535
    const int s = idx >> 5;
    const int i = idx & 31;
    const float p = (float)pos[s];
    const float inv = exp2f(-(float)i * 0.41524101186092f);  // 2*log2(1e4)/64
    float sn, cs;
    sincosf(p * inv, &sn, &cs);
    tab[idx] = make_float2(cs, sn);
}

// ---------------------------------------------------------------------------
// Fused QKV GEMM, 256x256 tile, BK=64, 8 waves, multi-phase counted-vmcnt
// schedule (T3+T4), LDS chunk-XOR swizzle (T2), setprio around MFMA (T5).
//
// LDS map (ushort units), pool[65536] = 128 KiB:
//   region(buf,mat,ks) at buf*32768 + mat*16384 + ks*8192, 16 KB each
//   within region: row (0..255) * 32 + chunk(0..3)*8, chunk stored XOR'd
//   with S(row) = (row&3)^((row&4)>>1)  (pre-swizzled global source, rule 21)
//
// Per K-tile (4 phases): ph0 = (mh0,ks0) reads A+B, ph1 = (mh1,ks0) reads A,
// ph2 = (mh0,ks1) reads A+B, ph3 = (mh1,ks1) reads A.  Each phase is the LAST
// reader of exactly one region, whose slot is re-staged one phase later:
//   ph0 stages Aks1(t+1) [other buffer], ph1 stages Bks0(t+2),
//   ph2 stages Aks0(t+2), ph3 stages Bks1(t+2)  [same buffer].
// Counted waits (steady state 5 regions = 10 loads in flight):
//   end-ph1: vmcnt(10) guarantees Aks1(t)/Bks1(t) landed (for ph2/ph3)
//   end-ph3: vmcnt(10) guarantees Aks0(t+1)/Bks0(t+1) landed (for next ph0/ph1)
// Both sit BEFORE a barrier so the guarantee is collective. Drain tail uses
// exact counts (8/4/0) since late stages are skipped.
// ---------------------------------------------------------------------------
#define QKV_BARRIER() do { asm volatile("" ::: "memory"); \
                           __builtin_amdgcn_s_barrier(); } while (0)
#define QKV_LGKM0()   do { asm volatile("s_waitcnt lgkmcnt(0)" ::: "memory"); \
                           __builtin_amdgcn_sched_barrier(0); } while (0)

#define PH_READ_A(MH, KS)                                                     \
    {                                                                         \
        const ushort* pA_ = pool + buf + (KS) * 8192 +                        \
                            (wm + (MH) * 64 + l16) * 32 + chq;                \
        _Pragma("unroll")                                                     \
        for (int im = 0; im < 4; im++)                                        \
            af[im] = *reinterpret_cast<const bf16x8*>(pA_ + im * 512);        \
    }
#define PH_READ_B(KS)                                                         \
    {                                                                         \
        const ushort* pB_ = pool + buf + 16384 + (KS) * 8192 +                \
                            (wn + l16) * 32 + chq;                            \
        _Pragma("unroll")                                                     \
        for (int jn = 0; jn < 4; jn++)                                        \
            bf[jn] = *reinterpret_cast<const bf16x8*>(pB_ + jn * 512);        \
    }
#define PH_MFMA(MH)                                                           \
    __builtin_amdgcn_s_setprio(1);                                            \
    _Pragma("unroll")                                                         \
    for (int im = 0; im < 4; im++)                                            \
        _Pragma("unroll")                                                     \
        for (int jn = 0; jn < 4; jn++)                                        \
            acc[(MH) * 4 + im][jn] = __builtin_amdgcn_mfma_f32_16x16x32_bf16( \
                af[im], bf[jn], acc[(MH) * 4 + im][jn], 0, 0, 0);             \
    __builtin_amdgcn_s_setprio(0);

__global__ __launch_bounds__(512, 2)
void gemm_qkv(const ushort* __restrict__ A, const ushort* __restrict__ B,
              ushort* __restrict__ C, const float2* __restrict__ tab) {
    __shared__ __align__(16) ushort pool[65536];   // 128 KiB

    // bijective XCD remap: each XCD gets 2 full A-stripes (by pairs) x 12 bx
    const int orig = blockIdx.y * gridDim.x + blockIdx.x;   // 0..191
    const int xcd  = orig & 7;
    const int ixd  = orig >> 3;                             // 0..23
    const int by   = xcd * 2 + (ixd / 12);
    const int bx   = ixd % 12;
    const int m0   = by * 256;
    const int n0   = bx * 256;

    const int tid  = threadIdx.x;
    const int lane = tid & 63;
    const int w    = tid >> 6;
    const int l16  = lane & 15;
    const int quad = lane >> 4;
    const int wm   = (w >> 2) * 128;    // 2 wave-rows
    const int wn   = (w & 3) * 64;      // 4 wave-cols
    // read-side swizzled chunk offset (row&7 == l16&7 for all frag reads)
    const int chq  = (quad ^ ((l16 & 3) ^ ((l16 & 4) >> 1))) << 3;
    // staging coords: thread covers one 16B chunk per issue
    const int srow = tid >> 2;          // 0..127
    const int ssc  = (tid & 3) ^ ((srow & 3) ^ ((srow & 4) >> 1));

    // stage one 16 KB region (mat: 0=A rows m0.., 1=B rows n0..; ks stripe)
    auto stage = [&](int mat, int tt, int ks) {
        const ushort* G = mat ? B : A;
        const int rb = mat ? n0 : m0;
        const int gc = tt * 64 + ks * 32 + ssc * 8;
        const int lb = ((tt & 1) << 15) + (mat << 14) + (ks << 13);
        #pragma unroll
        for (int issue = 0; issue < 2; issue++) {
            const int row = issue * 128 + srow;   // row&7 == srow&7
            load16_lds(G + (size_t)(rb + row) * DMODEL + gc,
                       &pool[lb + issue * 4096 + tid * 8]);
        }
    };

    // prologue: tiles 0 and 1, order [B ks0, A ks0, B ks1, A ks1] per tile
    stage(1, 0, 0); stage(0, 0, 0); stage(1, 0, 1); stage(0, 0, 1);
    stage(1, 1, 0); stage(0, 1, 0); stage(1, 1, 1); stage(0, 1, 1);

    f32x4 acc[8][4];
    #pragma unroll
    for (int i = 0; i < 8; i++)
        #pragma unroll
        for (int j = 0; j < 4; j++) acc[i][j] = (f32x4){0.f, 0.f, 0.f, 0.f};

    asm volatile("s_waitcnt vmcnt(8)" ::: "memory");  // tile 0 landed
    __builtin_amdgcn_s_barrier();

    bf16x8 af[4], bf[4];

    #pragma unroll 1
    for (int t = 0; t < 16; t++) {
        const int buf = (t & 1) << 15;
        // ---- ph0: (mh0, ks0)
        PH_READ_A(0, 0);
        PH_READ_B(0);
        if (t >= 1 && t <= 14) stage(0, t + 1, 1);    // Aks1(t+1) -> other buf
        QKV_BARRIER();
        QKV_LGKM0();
        PH_MFMA(0);
        QKV_BARRIER();
        // ---- ph1: (mh1, ks0)
        PH_READ_A(1, 0);
        if (t <= 13) stage(1, t + 2, 0);              // Bks0(t+2)
        QKV_BARRIER();
        QKV_LGKM0();
        PH_MFMA(1);
        if (t <= 13)      { asm volatile("s_waitcnt vmcnt(10)" ::: "memory"); }
        else if (t == 14) { asm volatile("s_waitcnt vmcnt(8)"  ::: "memory"); }
        else              { asm volatile("s_waitcnt vmcnt(0)"  ::: "memory"); }
        QKV_BARRIER();
        // ---- ph2: (mh0, ks1)
        PH_READ_A(0, 1);
        PH_READ_B(1);
        if (t <= 13) stage(0, t + 2, 0);              // Aks0(t+2)
        QKV_BARRIER();
        QKV_LGKM0();
        PH_MFMA(0);
        QKV_BARRIER();
        // ---- ph3: (mh1, ks1)
        PH_READ_A(1, 1);
        if (t <= 13) stage(1, t + 2, 1);              // Bks1(t+2)
        QKV_BARRIER();
        QKV_LGKM0();
        PH_MFMA(1);
        if (t <= 13)      { asm volatile("s_waitcnt vmcnt(10)" ::: "memory"); }
        else if (t == 14) { asm volatile("s_waitcnt vmcnt(4)"  ::: "memory"); }
        QKV_BARRIER();
    }

    const int nbase  = n0 + wn;
    const int tensor = nbase >> 10;        // wave-uniform (block-uniform)
    const int hh     = (nbase & 1023) >> 6;
    if (tensor < 2) {
        // ---- q/k epilogue with fused RoPE ----
        ushort* Dt = C + (size_t)tensor * ((size_t)MROWS * DMODEL);
        #pragma unroll
        for (int i = 0; i < 8; i++)
            #pragma unroll
            for (int r = 0; r < 4; r++) {
                const int m  = m0 + wm + i * 16 + quad * 4 + r;
                const int bb = m >> 11;
                const int ss = m & (SEQ - 1);
                const float2* trow = tab + ss * 32;
                #pragma unroll
                for (int j = 0; j < 4; j++) {
                    const int f = j * 16 + l16;          // dh 0..63
                    const float2 cs = trow[f >> 1];
                    const float val = acc[i][j][r];
                    const float prt = __shfl_xor(val, 1, 64);
                    const float out = (f & 1) ? (prt * cs.y + val * cs.x)
                                              : (val * cs.x - prt * cs.y);
                    Dt[(((size_t)(bb * NHEAD + hh)) * SEQ + ss) * DHEAD + f] =
                        bf16u(out);
                }
            }
    } else {
        // ---- V^T epilogue: wave-private swizzled LDS transpose ----
        // pool free: last phase's barrier retired all MFMA ds_reads
        ushort* Tw = pool + w * 8192;   // 16 KB per wave
        #pragma unroll
        for (int i = 0; i < 8; i++)
            #pragma unroll
            for (int j = 0; j < 4; j++) {
                const int f  = j * 16 + l16;
                const int sx = (f & 7) << 3;
                #pragma unroll
                for (int r = 0; r < 4; r += 2) {
                    const int ml = i * 16 + quad * 4 + r;
                    ushort2 pk;
                    pk.x = bf16u(acc[i][j][r]);
                    pk.y = bf16u(acc[i][j][r + 1]);
                    *reinterpret_cast<ushort2*>(&Tw[f * 128 + (ml ^ sx)]) = pk;
                }
            }
        asm volatile("s_waitcnt lgkmcnt(0)" ::: "memory");
        ushort* Dv = C + 2 * ((size_t)MROWS * DMODEL);
        const int c  = lane & 15;        // m-chunk (8 elems)
        const int fb = lane >> 4;        // f sub-row 0..3
        #pragma unroll
        for (int rr = 0; rr < 16; rr++) {
            const int fl = rr * 4 + fb;
            const uint4 v = *reinterpret_cast<const uint4*>(
                &Tw[fl * 128 + ((c << 3) ^ ((fl & 7) << 3))]);
            *reinterpret_cast<uint4*>(
                &Dv[(size_t)(hh * 64 + fl) * MROWS + m0 + wm + (c << 3)]) = v;
        }
    }
}

// ---------------------------------------------------------------------------
// Output GEMM, 64x128 tile, double-buffered. A in [b,h,s,dh], f32 out.
// ---------------------------------------------------------------------------
__global__ __launch_bounds__(256)
void gemm_out64(const ushort* __restrict__ A, const ushort* __restrict__ B,
                float* __restrict__ C) {
    __shared__ __align__(16) ushort pool[12288];   // As[2][2048] Bs[2][4096]
    ushort* As = pool;
    ushort* Bs = pool + 4096;
    const int tid  = threadIdx.x;
    const int m0   = blockIdx.y * 64;
    const int n0   = blockIdx.x * 128;
    const int lane = tid & 63;
    const int w    = tid >> 6;
    const int l16  = lane & 15;
    const int quad = lane >> 4;
    const int wm   = (w >> 1) * 32;
    const int wn   = (w & 1) * 64;
    const int srow = tid >> 2;        // 0..63
    const int scol = (tid & 3) * 8;

    // A gather address (k -> (h,dh)) for row srow
    const int am  = m0 + srow;
    const int abb = am >> 11;
    const int ass = am & (SEQ - 1);
    const size_t abase = ((size_t)(abb * NHEAD)) * SEQ * DHEAD + (size_t)ass * DHEAD;

    f32x4 acc[2][4];
    #pragma unroll
    for (int i = 0; i < 2; i++)
        #pragma unroll
        for (int j = 0; j < 4; j++) acc[i][j] = (f32x4){0.f, 0.f, 0.f, 0.f};

    // prologue: K-tile 0 -> buffer 0
    {
        const int h = scol >> 6, dh = scol & 63;
        load16_lds(A + abase + (size_t)h * SEQ * DHEAD + dh, &As[srow * 32 + scol]);
        #pragma unroll
        for (int half = 0; half < 2; half++) {
            const int row = srow + half * 64;
            load16_lds(B + (size_t)(n0 + row) * DMODEL + scol, &Bs[row * 32 + scol]);
        }
    }

    for (int t = 0; t < 32; t++) {
        const int bf = t & 1;
        __syncthreads();
        if (t + 1 < 32) {
            const int k0 = (t + 1) * 32;
            const int kk = k0 + scol;
            const int h = kk >> 6, dh = kk & 63;
            load16_lds(A + abase + (size_t)h * SEQ * DHEAD + dh,
                       &As[(bf ^ 1) * 2048 + srow * 32 + scol]);
            #pragma unroll
            for (int half = 0; half < 2; half++) {
                const int row = srow + half * 64;
                load16_lds(B + (size_t)(n0 + row) * DMODEL + k0 + scol,
                           &Bs[(bf ^ 1) * 4096 + row * 32 + scol]);
            }
        }
        const int oa = bf * 2048, ob_ = bf * 4096;
        bf16x8 af[2], bfr[4];
        #pragma unroll
        for (int s = 0; s < 2; s++)
            af[s] = *reinterpret_cast<const bf16x8*>(
                &As[oa + (wm + s * 16 + l16) * 32 + quad * 8]);
        #pragma unroll
        for (int s = 0; s < 4; s++)
            bfr[s] = *reinterpret_cast<const bf16x8*>(
                &Bs[ob_ + (wn + s * 16 + l16) * 32 + quad * 8]);
        #pragma unroll
        for (int i = 0; i < 2; i++)
            #pragma unroll
            for (int j = 0; j < 4; j++)
                acc[i][j] = __builtin_amdgcn_mfma_f32_16x16x32_bf16(
                    af[i], bfr[j], acc[i][j], 0, 0, 0);
    }
    #pragma unroll
    for (int i = 0; i < 2; i++)
        #pragma unroll
        for (int r = 0; r < 4; r++) {
            const int m = m0 + wm + i * 16 + quad * 4 + r;
            #pragma unroll
            for (int j = 0; j < 4; j++)
                C[(size_t)m * DMODEL + n0 + wn + j * 16 + l16] = acc[i][j][r];
        }
}

// ---------------------------------------------------------------------------
// MFMA flash attention v6 (unchanged): single-barrier async-DMA
// double-buffer + max-free exp2-domain softmax.
// ---------------------------------------------------------------------------
__global__ __launch_bounds__(256)
void attn_mfma6(const ushort* __restrict__ qb, const ushort* __restrict__ kb,
                const ushort* __restrict__ vtg, ushort* __restrict__ ob) {
    __shared__ __align__(16) ushort Ks[2][4096];
    __shared__ __align__(16) ushort Vs[2][4096];
    __shared__ ushort Pb[4][16][72];

    const int bh   = blockIdx.x;
    const int b    = bh >> 4;
    const int h    = bh & 15;
    const int qt   = (gridDim.y - 1) - blockIdx.y;
    const int tid  = threadIdx.x;
    const int w    = tid >> 6;
    const int lane = tid & 63;
    const int l16  = lane & 15;
    const int quad = lane >> 4;
    const size_t base = (size_t)bh * SEQ * DHEAD;

    const int qlo = qt * 64 + w * 16;

    const float SC = 0.125f * 1.44269504088896f;
    bf16x8 qa[2];
    {
        const size_t qo = base + (size_t)(qlo + l16) * DHEAD + quad * 8;
        qa[0] = *reinterpret_cast<const bf16x8*>(qb + qo);
        qa[1] = *reinterpret_cast<const bf16x8*>(qb + qo + 32);
        #pragma unroll
        for (int j = 0; j < 8; j++) {
            qa[0][j] = (__bf16)(SC * (float)qa[0][j]);
            qa[1][j] = (__bf16)(SC * (float)qa[1][j]);
        }
    }

    f32x4 oacc[4];
    #pragma unroll
    for (int s = 0; s < 4; s++) oacc[s] = (f32x4){0.f, 0.f, 0.f, 0.f};
    float l_ = 0.f;

    const int c0 = tid,        r0 = c0 >> 3, g0 = (c0 & 7) ^ (r0 & 7);
    const int c1 = 256 + tid,  r1 = c1 >> 3, g1 = (c1 & 7) ^ (r1 & 7);
    const ushort* kg0 = kb + base + (size_t)r0 * DHEAD + g0 * 8;
    const ushort* kg1 = kb + base + (size_t)r1 * DHEAD + g1 * 8;
    const ushort* vg0 = vtg + (size_t)(h * DHEAD + r0) * MROWS + b * SEQ + g0 * 8;
    const ushort* vg1 = vtg + (size_t)(h * DHEAD + r1) * MROWS + b * SEQ + g1 * 8;

    int koff[2][4];
    #pragma unroll
    for (int half = 0; half < 2; half++)
        #pragma unroll
        for (int sub = 0; sub < 4; sub++)
            koff[half][sub] = (sub * 16 + l16) * 64 +
                              (((half * 4 + quad) ^ (l16 & 7)) * 8);

    load16_lds(kg0, &Ks[0][c0 * 8]);
    load16_lds(kg1, &Ks[0][c1 * 8]);
    load16_lds(vg0, &Vs[0][c0 * 8]);
    load16_lds(vg1, &Vs[0][c1 * 8]);

    const int T = qt + 1;
    for (int t = 0; t < T; t++) {
        const int bf = t & 1;
        __syncthreads();
        if (t + 1 < T) {
            const size_t ko = (size_t)(t + 1) * 64 * DHEAD;
            const int    vo = (t + 1) * 64;
            load16_lds(kg0 + ko, &Ks[bf ^ 1][c0 * 8]);
            load16_lds(kg1 + ko, &Ks[bf ^ 1][c1 * 8]);
            load16_lds(vg0 + vo, &Vs[bf ^ 1][c0 * 8]);
            load16_lds(vg1 + vo, &Vs[bf ^ 1][c1 * 8]);
        }

        const bool diag = (t == qt);
        const int nsub = diag ? (w + 1) : 4;
        const int nhv  = diag ? ((w >> 1) + 1) : 2;

        f32x4 sacc[4];
        #pragma unroll
        for (int s = 0; s < 4; s++) sacc[s] = (f32x4){0.f, 0.f, 0.f, 0.f};
        #pragma unroll
        for (int half = 0; half < 2; half++)
            #pragma unroll
            for (int sub = 0; sub < 4; sub++)
                if (sub < nsub) {
                    const bf16x8 kf = *reinterpret_cast<const bf16x8*>(
                        &Ks[bf][koff[half][sub]]);
                    sacc[sub] = __builtin_amdgcn_mfma_f32_16x16x32_bf16(
                        kf, qa[half], sacc[sub], 0, 0, 0);
                }

        float ev[4][4];
        if (diag) {
            const int thr = qlo + l16 - t * 64;
            #pragma unroll
            for (int sub = 0; sub < 4; sub++)
                #pragma unroll
                for (int r = 0; r < 4; r++) {
                    const float e = (sub * 16 + quad * 4 + r <= thr)
                                        ? exp2f(sacc[sub][r]) : 0.f;
                    ev[sub][r] = e;
                    l_ += e;
                }
        } else {
            #pragma unroll
            for (int sub = 0; sub < 4; sub++)
                #pragma unroll
                for (int r = 0; r < 4; r++) {
                    const float e = exp2f(sacc[sub][r]);
                    ev[sub][r] = e;
                    l_ += e;
                }
        }

        #pragma unroll
        for (int sub = 0; sub < 4; sub++) {
            ushort4 pk;
            pk.x = bf16u(ev[sub][0]); pk.y = bf16u(ev[sub][1]);
            pk.z = bf16u(ev[sub][2]); pk.w = bf16u(ev[sub][3]);
            *reinterpret_cast<ushort4*>(&Pb[w][l16][sub * 16 + quad * 4]) = pk;
        }
        bf16x8 pa[2];
        pa[0] = *reinterpret_cast<const bf16x8*>(&Pb[w][l16][quad * 8]);
        pa[1] = *reinterpret_cast<const bf16x8*>(&Pb[w][l16][32 + quad * 8]);

        #pragma unroll
        for (int hk = 0; hk < 2; hk++) {
            if (hk >= nhv) break;
            #pragma unroll
            for (int sf = 0; sf < 4; sf++) {
                const bf16x8 vf = *reinterpret_cast<const bf16x8*>(
                    &Vs[bf][koff[hk][sf]]);
                oacc[sf] = __builtin_amdgcn_mfma_f32_16x16x32_bf16(
                    pa[hk], vf, oacc[sf], 0, 0, 0);
            }
        }
    }

    l_ += __shfl_xor(l_, 16, 64);
    l_ += __shfl_xor(l_, 32, 64);
    float inv[4];
    #pragma unroll
    for (int r = 0; r < 4; r++) inv[r] = 1.f / __shfl(l_, quad * 4 + r, 64);
    #pragma unroll
    for (int sub = 0; sub < 4; sub++)
        #pragma unroll
        for (int r = 0; r < 4; r++) {
            const int q = qlo + quad * 4 + r;
            ob[base + (size_t)q * DHEAD + sub * 16 + l16] =
                bf16u(oacc[sub][r] * inv[r]);
        }
}

// ---------------------------------------------------------------------------
extern "C" void kernel_launch(void* const* d_in, const int* in_sizes, int n_in,
                              void* d_out, int out_size, void* d_ws, size_t ws_size,
                              hipStream_t stream) {
    const float* x  = (const float*)d_in[0];
    const float* Wq = (const float*)d_in[1];
    const float* Wk = (const float*)d_in[2];
    const float* Wv = (const float*)d_in[3];
    const float* Wo = (const float*)d_in[4];
    const int* pos = (const int*)d_in[5];

    const size_t TEN = (size_t)MROWS * DMODEL;   // 4M elements
    const size_t WEL = (size_t)DMODEL * DMODEL;  // 1M elements
    ushort* xb   = (ushort*)d_ws;      // 8 MB
    ushort* Wqkv = xb + TEN;           // 8 MB (Wq,Wk,Wv,Wo contiguous)
    ushort* Wob  = Wqkv + 3 * WEL;
    ushort* qb   = Wob + WEL;          // 8 MB each; kb, vtb contiguous
    ushort* kb   = qb + TEN;
    ushort* vtb  = kb + TEN;           // V^T [1024][4096]
    ushort* ob   = vtb + TEN;
    float2* tab  = (float2*)(ob + TEN);  // 512 KB rope table

    dim3 blk(256);
    rope_tab<<<(SEQ * 32) / 256, blk, 0, stream>>>(pos, tab);
    cast_f32_bf16<<<TEN / (8 * 256), blk, 0, stream>>>(x, xb, (int)TEN);
    dim3 gcw(WEL / (8 * 256), 4);
    cast_w4<<<gcw, blk, 0, stream>>>(Wq, Wk, Wv, Wo, Wqkv);

    dim3 gqkv(3 * DMODEL / 256, MROWS / 256);   // (12, 16) = 192 blocks
    gemm_qkv<<<gqkv, dim3(512), 0, stream>>>(xb, Wqkv, qb, tab);

    dim3 gattn(BATCH * NHEAD, SEQ / 64);        // (32, 32)
    attn_mfma6<<<gattn, blk, 0, stream>>>(qb, kb, vtb, ob);

    dim3 gout(DMODEL / 128, MROWS / 64);        // (8, 64)
    gemm_out64<<<gout, blk, 0, stream>>>(ob, Wob, (float*)d_out);
}

// Round 2
// 184.788 us; speedup vs baseline: 1.0116x; 1.0082x over previous
//
#include <hip/hip_runtime.h>
#include <hip/hip_bf16.h>
#include <math.h>

#define DMODEL 1024
#define NHEAD  16
#define DHEAD  64
#define BATCH  2
#define SEQ    2048
#define MROWS  (BATCH * SEQ)   // 4096

typedef __attribute__((ext_vector_type(8))) __bf16 bf16x8;
typedef __attribute__((ext_vector_type(4))) float  f32x4;

// async global->LDS, 16 B per lane. LDS dest must be wave-uniform base + lane*16.
__device__ __forceinline__ void load16_lds(const ushort* g, ushort* l) {
    __builtin_amdgcn_global_load_lds(
        (const __attribute__((address_space(1))) unsigned int*)g,
        (__attribute__((address_space(3))) unsigned int*)l, 16, 0, 0);
}

__device__ __forceinline__ ushort bf16u(float v) {
    __hip_bfloat16 h = __float2bfloat16(v);
    return *reinterpret_cast<ushort*>(&h);
}

// ---------------------------------------------------------------------------
// fp32 -> bf16 casts
// ---------------------------------------------------------------------------
__global__ __launch_bounds__(256)
void cast_f32_bf16(const float* __restrict__ s, ushort* __restrict__ d, int n) {
    const int i = (blockIdx.x * 256 + threadIdx.x) * 8;
    if (i >= n) return;
    const f32x4 a = *reinterpret_cast<const f32x4*>(s + i);
    const f32x4 b = *reinterpret_cast<const f32x4*>(s + i + 4);
    bf16x8 o;
    #pragma unroll
    for (int j = 0; j < 4; j++) { o[j] = (__bf16)a[j]; o[4 + j] = (__bf16)b[j]; }
    *reinterpret_cast<bf16x8*>(d + i) = o;
}

__global__ __launch_bounds__(256)
void cast_w4(const float* __restrict__ w0, const float* __restrict__ w1,
             const float* __restrict__ w2, const float* __restrict__ w3,
             ushort* __restrict__ dst) {
    const float* src = (blockIdx.y == 0) ? w0 : (blockIdx.y == 1) ? w1
                     : (blockIdx.y == 2) ? w2 : w3;
    const int i = (blockIdx.x * 256 + threadIdx.x) * 8;
    const f32x4 a = *reinterpret_cast<const f32x4*>(src + i);
    const f32x4 b = *reinterpret_cast<const f32x4*>(src + i + 4);
    bf16x8 o;
    #pragma unroll
    for (int j = 0; j < 4; j++) { o[j] = (__bf16)a[j]; o[4 + j] = (__bf16)b[j]; }
    *reinterpret_cast<bf16x8*>(dst + (size_t)blockIdx.y * DMODEL * DMODEL + i) = o;
}

// ---------------------------------------------------------------------------
// RoPE cos/sin table: tab[s*32+i] = (cos, sin) of pos[s] * 10000^(-2i/64).
// ---------------------------------------------------------------------------
__global__ __launch_bounds__(256)
void rope_tab(const int* __restrict__ pos, float2* __restrict__ tab) {
    const int idx = blockIdx.x * 256 + threadIdx.x;   // 0..65535
    const int s = idx >> 5;
    const int i = idx & 31;
    const float p = (float)pos[s];
    const float inv = exp2f(-(float)i * 0.41524101186092f);  // 2*log2(1e4)/64
    float sn, cs;
    sincosf(p * inv, &sn, &cs);
    tab[idx] = make_float2(cs, sn);
}

// ---------------------------------------------------------------------------
// Fused QKV GEMM, 256x256 tile, BK=64, 8 waves.
// Round-2 structure: TWO phases per K-tile (ks0, ks1), 32 MFMA per phase.
// Per phase: {12 ds_read_b128 ; stage 2 regions ; barrier ; 32 MFMA ;
//             vmcnt(8) ; barrier}.  No explicit lgkmcnt drain: the MFMA
// register dependency forces ds_read completion before the closing barrier.
//
// LDS map (ushort units), pool[65536] = 128 KiB:
//   region(buf,mat,ks) at buf*32768 + mat*16384 + ks*8192, 16 KB each
//   within region: row (0..255) * 32 + chunk(0..3)*8, chunk XOR-swizzled with
//   S(row) = (row&3)^((row&4)>>1), applied on the pre-swizzled global source
//   (rule 21) and on the ds_read address.
//
// Stage schedule (one A-region + one B-region per phase):
//   P(t,0): stage AB(t+1,ks1)  [slot (buf^1,ks1), last read P(t-1,1)]
//   P(t,1): stage AB(t+2,ks0)  [slot (buf  ,ks0), last read P(t,0)]
// Steady-state wait vmcnt(8) at each phase end (12 outstanding -> forces the
// 2 regions (4 loads) needed by the NEXT phase; 3-phase prefetch span).
// Tail: end-P(14,1)=vmcnt(4), end-P(15,0)=vmcnt(0), others exact per trace.
// ---------------------------------------------------------------------------
#define QKV_BARRIER() do { asm volatile("" ::: "memory"); \
                           __builtin_amdgcn_s_barrier(); } while (0)

#define PH_READ_AB(KS)                                                        \
    {                                                                         \
        const ushort* pA_ = pool + buf + (KS) * 8192 + (wm + l16) * 32 + chq; \
        _Pragma("unroll")                                                     \
        for (int im = 0; im < 8; im++)                                        \
            af[im] = *reinterpret_cast<const bf16x8*>(pA_ + im * 512);        \
        const ushort* pB_ = pool + buf + 16384 + (KS) * 8192 +                \
                            (wn + l16) * 32 + chq;                            \
        _Pragma("unroll")                                                     \
        for (int jn = 0; jn < 4; jn++)                                        \
            bf[jn] = *reinterpret_cast<const bf16x8*>(pB_ + jn * 512);        \
    }

#define PH_MFMA2()                                                            \
    __builtin_amdgcn_s_setprio(1);                                            \
    _Pragma("unroll")                                                         \
    for (int im = 0; im < 8; im++)                                            \
        _Pragma("unroll")                                                     \
        for (int jn = 0; jn < 4; jn++)                                        \
            acc[im][jn] = __builtin_amdgcn_mfma_f32_16x16x32_bf16(            \
                af[im], bf[jn], acc[im][jn], 0, 0, 0);                        \
    __builtin_amdgcn_s_setprio(0);

__global__ __launch_bounds__(512, 2)
void gemm_qkv(const ushort* __restrict__ A, const ushort* __restrict__ B,
              ushort* __restrict__ C, const float2* __restrict__ tab) {
    __shared__ __align__(16) ushort pool[65536];   // 128 KiB

    // bijective XCD remap: each XCD gets 2 full A-stripes (by pairs) x 12 bx
    const int orig = blockIdx.y * gridDim.x + blockIdx.x;   // 0..191
    const int xcd  = orig & 7;
    const int ixd  = orig >> 3;                             // 0..23
    const int by   = xcd * 2 + (ixd / 12);
    const int bx   = ixd % 12;
    const int m0   = by * 256;
    const int n0   = bx * 256;

    const int tid  = threadIdx.x;
    const int lane = tid & 63;
    const int w    = tid >> 6;
    const int l16  = lane & 15;
    const int quad = lane >> 4;
    const int wm   = (w >> 2) * 128;    // 2 wave-rows
    const int wn   = (w & 3) * 64;      // 4 wave-cols
    // read-side swizzled chunk offset (row&7 == l16&7 for all frag reads)
    const int chq  = (quad ^ ((l16 & 3) ^ ((l16 & 4) >> 1))) << 3;
    // staging coords: thread covers one 16B chunk per issue
    const int srow = tid >> 2;          // 0..127
    const int ssc  = (tid & 3) ^ ((srow & 3) ^ ((srow & 4) >> 1));

    // hoisted staging bases (pre-swizzled global source)
    const ushort* gA = A + (size_t)(m0 + srow) * DMODEL + ssc * 8;
    const ushort* gB = B + (size_t)(n0 + srow) * DMODEL + ssc * 8;

    auto stageA = [&](int tt, int ks) {
        const int off = tt * 64 + ks * 32;
        const int lb  = ((tt & 1) << 15) + (ks << 13);
        load16_lds(gA + off,               &pool[lb + tid * 8]);
        load16_lds(gA + 128 * DMODEL + off, &pool[lb + 4096 + tid * 8]);
    };
    auto stageB = [&](int tt, int ks) {
        const int off = tt * 64 + ks * 32;
        const int lb  = ((tt & 1) << 15) + 16384 + (ks << 13);
        load16_lds(gB + off,               &pool[lb + tid * 8]);
        load16_lds(gB + 128 * DMODEL + off, &pool[lb + 4096 + tid * 8]);
    };

    // prologue: AB(0,0), AB(0,1), AB(1,0)  [12 loads]
    stageA(0, 0); stageB(0, 0);
    stageA(0, 1); stageB(0, 1);
    stageA(1, 0); stageB(1, 0);

    f32x4 acc[8][4];
    #pragma unroll
    for (int i = 0; i < 8; i++)
        #pragma unroll
        for (int j = 0; j < 4; j++) acc[i][j] = (f32x4){0.f, 0.f, 0.f, 0.f};

    asm volatile("s_waitcnt vmcnt(8)" ::: "memory");  // AB(0,0) landed
    __builtin_amdgcn_s_barrier();

    bf16x8 af[8], bf[4];

    #pragma unroll 1
    for (int t = 0; t < 16; t++) {
        const int buf = (t & 1) << 15;
        // ---- phase (t, ks0): 12 ds_read + stage AB(t+1,ks1) + 32 MFMA
        PH_READ_AB(0);
        if (t <= 14) { stageA(t + 1, 1); stageB(t + 1, 1); }
        QKV_BARRIER();
        PH_MFMA2();
        if (t <= 14) { asm volatile("s_waitcnt vmcnt(8)" ::: "memory"); }
        else         { asm volatile("s_waitcnt vmcnt(0)" ::: "memory"); }
        QKV_BARRIER();
        // ---- phase (t, ks1): 12 ds_read + stage AB(t+2,ks0) + 32 MFMA
        PH_READ_AB(1);
        if (t <= 13) { stageA(t + 2, 0); stageB(t + 2, 0); }
        QKV_BARRIER();
        PH_MFMA2();
        if (t <= 13)      { asm volatile("s_waitcnt vmcnt(8)" ::: "memory"); }
        else if (t == 14) { asm volatile("s_waitcnt vmcnt(4)" ::: "memory"); }
        QKV_BARRIER();
    }

    const int nbase  = n0 + wn;
    const int tensor = nbase >> 10;        // wave-uniform (block-uniform)
    const int hh     = (nbase & 1023) >> 6;
    if (tensor < 2) {
        // ---- q/k epilogue with fused RoPE ----
        ushort* Dt = C + (size_t)tensor * ((size_t)MROWS * DMODEL);
        #pragma unroll
        for (int i = 0; i < 8; i++)
            #pragma unroll
            for (int r = 0; r < 4; r++) {
                const int m  = m0 + wm + i * 16 + quad * 4 + r;
                const int bb = m >> 11;
                const int ss = m & (SEQ - 1);
                const float2* trow = tab + ss * 32;
                #pragma unroll
                for (int j = 0; j < 4; j++) {
                    const int f = j * 16 + l16;          // dh 0..63
                    const float2 cs = trow[f >> 1];
                    const float val = acc[i][j][r];
                    const float prt = __shfl_xor(val, 1, 64);
                    const float out = (f & 1) ? (prt * cs.y + val * cs.x)
                                              : (val * cs.x - prt * cs.y);
                    Dt[(((size_t)(bb * NHEAD + hh)) * SEQ + ss) * DHEAD + f] =
                        bf16u(out);
                }
            }
    } else {
        // ---- V^T epilogue: wave-private swizzled LDS transpose ----
        // pool free: last phase's barrier retired all MFMA ds_reads
        ushort* Tw = pool + w * 8192;   // 16 KB per wave
        #pragma unroll
        for (int i = 0; i < 8; i++)
            #pragma unroll
            for (int j = 0; j < 4; j++) {
                const int f  = j * 16 + l16;
                const int sx = (f & 7) << 3;
                #pragma unroll
                for (int r = 0; r < 4; r += 2) {
                    const int ml = i * 16 + quad * 4 + r;
                    ushort2 pk;
                    pk.x = bf16u(acc[i][j][r]);
                    pk.y = bf16u(acc[i][j][r + 1]);
                    *reinterpret_cast<ushort2*>(&Tw[f * 128 + (ml ^ sx)]) = pk;
                }
            }
        asm volatile("s_waitcnt lgkmcnt(0)" ::: "memory");
        ushort* Dv = C + 2 * ((size_t)MROWS * DMODEL);
        const int c  = lane & 15;        // m-chunk (8 elems)
        const int fb = lane >> 4;        // f sub-row 0..3
        #pragma unroll
        for (int rr = 0; rr < 16; rr++) {
            const int fl = rr * 4 + fb;
            const uint4 v = *reinterpret_cast<const uint4*>(
                &Tw[fl * 128 + ((c << 3) ^ ((fl & 7) << 3))]);
            *reinterpret_cast<uint4*>(
                &Dv[(size_t)(hh * 64 + fl) * MROWS + m0 + wm + (c << 3)]) = v;
        }
    }
}

// ---------------------------------------------------------------------------
// Output GEMM, 64x128 tile, double-buffered. A in [b,h,s,dh], f32 out.
// ---------------------------------------------------------------------------
__global__ __launch_bounds__(256)
void gemm_out64(const ushort* __restrict__ A, const ushort* __restrict__ B,
                float* __restrict__ C) {
    __shared__ __align__(16) ushort pool[12288];   // As[2][2048] Bs[2][4096]
    ushort* As = pool;
    ushort* Bs = pool + 4096;
    const int tid  = threadIdx.x;
    const int m0   = blockIdx.y * 64;
    const int n0   = blockIdx.x * 128;
    const int lane = tid & 63;
    const int w    = tid >> 6;
    const int l16  = lane & 15;
    const int quad = lane >> 4;
    const int wm   = (w >> 1) * 32;
    const int wn   = (w & 1) * 64;
    const int srow = tid >> 2;        // 0..63
    const int scol = (tid & 3) * 8;

    // A gather address (k -> (h,dh)) for row srow
    const int am  = m0 + srow;
    const int abb = am >> 11;
    const int ass = am & (SEQ - 1);
    const size_t abase = ((size_t)(abb * NHEAD)) * SEQ * DHEAD + (size_t)ass * DHEAD;

    f32x4 acc[2][4];
    #pragma unroll
    for (int i = 0; i < 2; i++)
        #pragma unroll
        for (int j = 0; j < 4; j++) acc[i][j] = (f32x4){0.f, 0.f, 0.f, 0.f};

    // prologue: K-tile 0 -> buffer 0
    {
        const int h = scol >> 6, dh = scol & 63;
        load16_lds(A + abase + (size_t)h * SEQ * DHEAD + dh, &As[srow * 32 + scol]);
        #pragma unroll
        for (int half = 0; half < 2; half++) {
            const int row = srow + half * 64;
            load16_lds(B + (size_t)(n0 + row) * DMODEL + scol, &Bs[row * 32 + scol]);
        }
    }

    for (int t = 0; t < 32; t++) {
        const int bf = t & 1;
        __syncthreads();
        if (t + 1 < 32) {
            const int k0 = (t + 1) * 32;
            const int kk = k0 + scol;
            const int h = kk >> 6, dh = kk & 63;
            load16_lds(A + abase + (size_t)h * SEQ * DHEAD + dh,
                       &As[(bf ^ 1) * 2048 + srow * 32 + scol]);
            #pragma unroll
            for (int half = 0; half < 2; half++) {
                const int row = srow + half * 64;
                load16_lds(B + (size_t)(n0 + row) * DMODEL + k0 + scol,
                           &Bs[(bf ^ 1) * 4096 + row * 32 + scol]);
            }
        }
        const int oa = bf * 2048, ob_ = bf * 4096;
        bf16x8 af[2], bfr[4];
        #pragma unroll
        for (int s = 0; s < 2; s++)
            af[s] = *reinterpret_cast<const bf16x8*>(
                &As[oa + (wm + s * 16 + l16) * 32 + quad * 8]);
        #pragma unroll
        for (int s = 0; s < 4; s++)
            bfr[s] = *reinterpret_cast<const bf16x8*>(
                &Bs[ob_ + (wn + s * 16 + l16) * 32 + quad * 8]);
        #pragma unroll
        for (int i = 0; i < 2; i++)
            #pragma unroll
            for (int j = 0; j < 4; j++)
                acc[i][j] = __builtin_amdgcn_mfma_f32_16x16x32_bf16(
                    af[i], bfr[j], acc[i][j], 0, 0, 0);
    }
    #pragma unroll
    for (int i = 0; i < 2; i++)
        #pragma unroll
        for (int r = 0; r < 4; r++) {
            const int m = m0 + wm + i * 16 + quad * 4 + r;
            #pragma unroll
            for (int j = 0; j < 4; j++)
                C[(size_t)m * DMODEL + n0 + wn + j * 16 + l16] = acc[i][j][r];
        }
}

// ---------------------------------------------------------------------------
// MFMA flash attention v6 (unchanged): single-barrier async-DMA
// double-buffer + max-free exp2-domain softmax.
// ---------------------------------------------------------------------------
__global__ __launch_bounds__(256)
void attn_mfma6(const ushort* __restrict__ qb, const ushort* __restrict__ kb,
                const ushort* __restrict__ vtg, ushort* __restrict__ ob) {
    __shared__ __align__(16) ushort Ks[2][4096];
    __shared__ __align__(16) ushort Vs[2][4096];
    __shared__ ushort Pb[4][16][72];

    const int bh   = blockIdx.x;
    const int b    = bh >> 4;
    const int h    = bh & 15;
    const int qt   = (gridDim.y - 1) - blockIdx.y;
    const int tid  = threadIdx.x;
    const int w    = tid >> 6;
    const int lane = tid & 63;
    const int l16  = lane & 15;
    const int quad = lane >> 4;
    const size_t base = (size_t)bh * SEQ * DHEAD;

    const int qlo = qt * 64 + w * 16;

    const float SC = 0.125f * 1.44269504088896f;
    bf16x8 qa[2];
    {
        const size_t qo = base + (size_t)(qlo + l16) * DHEAD + quad * 8;
        qa[0] = *reinterpret_cast<const bf16x8*>(qb + qo);
        qa[1] = *reinterpret_cast<const bf16x8*>(qb + qo + 32);
        #pragma unroll
        for (int j = 0; j < 8; j++) {
            qa[0][j] = (__bf16)(SC * (float)qa[0][j]);
            qa[1][j] = (__bf16)(SC * (float)qa[1][j]);
        }
    }

    f32x4 oacc[4];
    #pragma unroll
    for (int s = 0; s < 4; s++) oacc[s] = (f32x4){0.f, 0.f, 0.f, 0.f};
    float l_ = 0.f;

    const int c0 = tid,        r0 = c0 >> 3, g0 = (c0 & 7) ^ (r0 & 7);
    const int c1 = 256 + tid,  r1 = c1 >> 3, g1 = (c1 & 7) ^ (r1 & 7);
    const ushort* kg0 = kb + base + (size_t)r0 * DHEAD + g0 * 8;
    const ushort* kg1 = kb + base + (size_t)r1 * DHEAD + g1 * 8;
    const ushort* vg0 = vtg + (size_t)(h * DHEAD + r0) * MROWS + b * SEQ + g0 * 8;
    const ushort* vg1 = vtg + (size_t)(h * DHEAD + r1) * MROWS + b * SEQ + g1 * 8;

    int koff[2][4];
    #pragma unroll
    for (int half = 0; half < 2; half++)
        #pragma unroll
        for (int sub = 0; sub < 4; sub++)
            koff[half][sub] = (sub * 16 + l16) * 64 +
                              (((half * 4 + quad) ^ (l16 & 7)) * 8);

    load16_lds(kg0, &Ks[0][c0 * 8]);
    load16_lds(kg1, &Ks[0][c1 * 8]);
    load16_lds(vg0, &Vs[0][c0 * 8]);
    load16_lds(vg1, &Vs[0][c1 * 8]);

    const int T = qt + 1;
    for (int t = 0; t < T; t++) {
        const int bf = t & 1;
        __syncthreads();
        if (t + 1 < T) {
            const size_t ko = (size_t)(t + 1) * 64 * DHEAD;
            const int    vo = (t + 1) * 64;
            load16_lds(kg0 + ko, &Ks[bf ^ 1][c0 * 8]);
            load16_lds(kg1 + ko, &Ks[bf ^ 1][c1 * 8]);
            load16_lds(vg0 + vo, &Vs[bf ^ 1][c0 * 8]);
            load16_lds(vg1 + vo, &Vs[bf ^ 1][c1 * 8]);
        }

        const bool diag = (t == qt);
        const int nsub = diag ? (w + 1) : 4;
        const int nhv  = diag ? ((w >> 1) + 1) : 2;

        f32x4 sacc[4];
        #pragma unroll
        for (int s = 0; s < 4; s++) sacc[s] = (f32x4){0.f, 0.f, 0.f, 0.f};
        #pragma unroll
        for (int half = 0; half < 2; half++)
            #pragma unroll
            for (int sub = 0; sub < 4; sub++)
                if (sub < nsub) {
                    const bf16x8 kf = *reinterpret_cast<const bf16x8*>(
                        &Ks[bf][koff[half][sub]]);
                    sacc[sub] = __builtin_amdgcn_mfma_f32_16x16x32_bf16(
                        kf, qa[half], sacc[sub], 0, 0, 0);
                }

        float ev[4][4];
        if (diag) {
            const int thr = qlo + l16 - t * 64;
            #pragma unroll
            for (int sub = 0; sub < 4; sub++)
                #pragma unroll
                for (int r = 0; r < 4; r++) {
                    const float e = (sub * 16 + quad * 4 + r <= thr)
                                        ? exp2f(sacc[sub][r]) : 0.f;
                    ev[sub][r] = e;
                    l_ += e;
                }
        } else {
            #pragma unroll
            for (int sub = 0; sub < 4; sub++)
                #pragma unroll
                for (int r = 0; r < 4; r++) {
                    const float e = exp2f(sacc[sub][r]);
                    ev[sub][r] = e;
                    l_ += e;
                }
        }

        #pragma unroll
        for (int sub = 0; sub < 4; sub++) {
            ushort4 pk;
            pk.x = bf16u(ev[sub][0]); pk.y = bf16u(ev[sub][1]);
            pk.z = bf16u(ev[sub][2]); pk.w = bf16u(ev[sub][3]);
            *reinterpret_cast<ushort4*>(&Pb[w][l16][sub * 16 + quad * 4]) = pk;
        }
        bf16x8 pa[2];
        pa[0] = *reinterpret_cast<const bf16x8*>(&Pb[w][l16][quad * 8]);
        pa[1] = *reinterpret_cast<const bf16x8*>(&Pb[w][l16][32 + quad * 8]);

        #pragma unroll
        for (int hk = 0; hk < 2; hk++) {
            if (hk >= nhv) break;
            #pragma unroll
            for (int sf = 0; sf < 4; sf++) {
                const bf16x8 vf = *reinterpret_cast<const bf16x8*>(
                    &Vs[bf][koff[hk][sf]]);
                oacc[sf] = __builtin_amdgcn_mfma_f32_16x16x32_bf16(
                    pa[hk], vf, oacc[sf], 0, 0, 0);
            }
        }
    }

    l_ += __shfl_xor(l_, 16, 64);
    l_ += __shfl_xor(l_, 32, 64);
    float inv[4];
    #pragma unroll
    for (int r = 0; r < 4; r++) inv[r] = 1.f / __shfl(l_, quad * 4 + r, 64);
    #pragma unroll
    for (int sub = 0; sub < 4; sub++)
        #pragma unroll
        for (int r = 0; r < 4; r++) {
            const int q = qlo + quad * 4 + r;
            ob[base + (size_t)q * DHEAD + sub * 16 + l16] =
                bf16u(oacc[sub][r] * inv[r]);
        }
}

// ---------------------------------------------------------------------------
extern "C" void kernel_launch(void* const* d_in, const int* in_sizes, int n_in,
                              void* d_out, int out_size, void* d_ws, size_t ws_size,
                              hipStream_t stream) {
    const float* x  = (const float*)d_in[0];
    const float* Wq = (const float*)d_in[1];
    const float* Wk = (const float*)d_in[2];
    const float* Wv = (const float*)d_in[3];
    const float* Wo = (const float*)d_in[4];
    const int* pos = (const int*)d_in[5];

    const size_t TEN = (size_t)MROWS * DMODEL;   // 4M elements
    const size_t WEL = (size_t)DMODEL * DMODEL;  // 1M elements
    ushort* xb   = (ushort*)d_ws;      // 8 MB
    ushort* Wqkv = xb + TEN;           // 8 MB (Wq,Wk,Wv,Wo contiguous)
    ushort* Wob  = Wqkv + 3 * WEL;
    ushort* qb   = Wob + WEL;          // 8 MB each; kb, vtb contiguous
    ushort* kb   = qb + TEN;
    ushort* vtb  = kb + TEN;           // V^T [1024][4096]
    ushort* ob   = vtb + TEN;
    float2* tab  = (float2*)(ob + TEN);  // 512 KB rope table

    dim3 blk(256);
    rope_tab<<<(SEQ * 32) / 256, blk, 0, stream>>>(pos, tab);
    cast_f32_bf16<<<TEN / (8 * 256), blk, 0, stream>>>(x, xb, (int)TEN);
    dim3 gcw(WEL / (8 * 256), 4);
    cast_w4<<<gcw, blk, 0, stream>>>(Wq, Wk, Wv, Wo, Wqkv);

    dim3 gqkv(3 * DMODEL / 256, MROWS / 256);   // (12, 16) = 192 blocks
    gemm_qkv<<<gqkv, dim3(512), 0, stream>>>(xb, Wqkv, qb, tab);

    dim3 gattn(BATCH * NHEAD, SEQ / 64);        // (32, 32)
    attn_mfma6<<<gattn, blk, 0, stream>>>(qb, kb, vtb, ob);

    dim3 gout(DMODEL / 128, MROWS / 64);        // (8, 64)
    gemm_out64<<<gout, blk, 0, stream>>>(ob, Wob, (float*)d_out);
}

// Round 3
// 181.534 us; speedup vs baseline: 1.0297x; 1.0179x over previous
//
#include <hip/hip_runtime.h>
#include <hip/hip_bf16.h>
#include <math.h>

#define DMODEL 1024
#define NHEAD  16
#define DHEAD  64
#define BATCH  2
#define SEQ    2048
#define MROWS  (BATCH * SEQ)   // 4096

typedef __attribute__((ext_vector_type(8))) __bf16 bf16x8;
typedef __attribute__((ext_vector_type(4))) float  f32x4;

// async global->LDS, 16 B per lane. LDS dest must be wave-uniform base + lane*16.
__device__ __forceinline__ void load16_lds(const ushort* g, ushort* l) {
    __builtin_amdgcn_global_load_lds(
        (const __attribute__((address_space(1))) unsigned int*)g,
        (__attribute__((address_space(3))) unsigned int*)l, 16, 0, 0);
}

__device__ __forceinline__ ushort bf16u(float v) {
    __hip_bfloat16 h = __float2bfloat16(v);
    return *reinterpret_cast<ushort*>(&h);
}

// ---------------------------------------------------------------------------
// fp32 -> bf16 casts
// ---------------------------------------------------------------------------
__global__ __launch_bounds__(256)
void cast_f32_bf16(const float* __restrict__ s, ushort* __restrict__ d, int n) {
    const int i = (blockIdx.x * 256 + threadIdx.x) * 8;
    if (i >= n) return;
    const f32x4 a = *reinterpret_cast<const f32x4*>(s + i);
    const f32x4 b = *reinterpret_cast<const f32x4*>(s + i + 4);
    bf16x8 o;
    #pragma unroll
    for (int j = 0; j < 4; j++) { o[j] = (__bf16)a[j]; o[4 + j] = (__bf16)b[j]; }
    *reinterpret_cast<bf16x8*>(d + i) = o;
}

__global__ __launch_bounds__(256)
void cast_w4(const float* __restrict__ w0, const float* __restrict__ w1,
             const float* __restrict__ w2, const float* __restrict__ w3,
             ushort* __restrict__ dst) {
    const float* src = (blockIdx.y == 0) ? w0 : (blockIdx.y == 1) ? w1
                     : (blockIdx.y == 2) ? w2 : w3;
    const int i = (blockIdx.x * 256 + threadIdx.x) * 8;
    const f32x4 a = *reinterpret_cast<const f32x4*>(src + i);
    const f32x4 b = *reinterpret_cast<const f32x4*>(src + i + 4);
    bf16x8 o;
    #pragma unroll
    for (int j = 0; j < 4; j++) { o[j] = (__bf16)a[j]; o[4 + j] = (__bf16)b[j]; }
    *reinterpret_cast<bf16x8*>(dst + (size_t)blockIdx.y * DMODEL * DMODEL + i) = o;
}

// ---------------------------------------------------------------------------
// RoPE cos/sin table: tab[s*32+i] = (cos, sin) of pos[s] * 10000^(-2i/64).
// ---------------------------------------------------------------------------
__global__ __launch_bounds__(256)
void rope_tab(const int* __restrict__ pos, float2* __restrict__ tab) {
    const int idx = blockIdx.x * 256 + threadIdx.x;   // 0..65535
    const int s = idx >> 5;
    const int i = idx & 31;
    const float p = (float)pos[s];
    const float inv = exp2f(-(float)i * 0.41524101186092f);  // 2*log2(1e4)/64
    float sn, cs;
    sincosf(p * inv, &sn, &cs);
    tab[idx] = make_float2(cs, sn);
}

// ---------------------------------------------------------------------------
// Fused QKV GEMM, 256x256 tile, BK=64, 8 waves.
// Round-3: register-software-pipelined phases. Phase P's ds_reads happen
// DURING phase P-1's MFMA cluster, so LDS latency is fully hidden:
//   phase body = { stage(4 gloads) ; read ah(cur A-hi, 4 b128) ;
//                  MFMA g1: al x bc (16) ;
//                  read al(next A-lo) + bn(next B) (8 b128) ;
//                  MFMA g2: ah x bc (16) ; vmcnt(4) ; barrier }
// A-lo uses a single register set (dead after g1; HW WAR scoreboard makes the
// overwrite safe); B is double-buffered (bc/bn alternate per phase).
//
// LDS map (ushort units), pool[65536] = 128 KiB:
//   region(buf,mat,ks) at buf*32768 + mat*16384 + ks*8192, 16 KB each
//   within region: row (0..255) * 32 + chunk(0..3)*8, chunk XOR-swizzled with
//   S(row) = (row&3)^((row&4)>>1), applied on the pre-swizzled global source
//   (rule 21) and on the ds_read address.
//
// Stage schedule: P0(t) stages AB(t+1,ks1) (t<=14); P1(t) stages AB(t+2,ks0)
// (t<=13). Slot being staged was last READ one full phase + 2 barriers ago.
// vmcnt ledger (4 loads/phase/wave, in-order retirement):
//   end-P0(t): outstanding = P1(t-1)4 + P0(t)4 -> vmcnt(4) retires AB(t+1,ks0)
//              (needed by P1(t)'s next-phase reads)        [t<=14; t=15 skip]
//   end-P1(t): outstanding = P0(t)4 + P1(t)4 -> vmcnt(4) retires AB(t+1,ks1)
//              (needed by P0(t+1)'s reads)   [t<=13; t=14 vmcnt(0); t=15 skip]
// ---------------------------------------------------------------------------
#define QKV_BARRIER() do { asm volatile("" ::: "memory"); \
                           __builtin_amdgcn_s_barrier(); } while (0)

#define RD4(dst, p_)                                                          \
    _Pragma("unroll")                                                         \
    for (int rr_ = 0; rr_ < 4; rr_++)                                         \
        dst[rr_] = *reinterpret_cast<const bf16x8*>((p_) + rr_ * 512);

#define MFMA_G(AFR, BFR, IOFF)                                                \
    __builtin_amdgcn_s_setprio(1);                                            \
    _Pragma("unroll")                                                         \
    for (int im_ = 0; im_ < 4; im_++)                                         \
        _Pragma("unroll")                                                     \
        for (int jn_ = 0; jn_ < 4; jn_++)                                     \
            acc[(IOFF) + im_][jn_] = __builtin_amdgcn_mfma_f32_16x16x32_bf16( \
                AFR[im_], BFR[jn_], acc[(IOFF) + im_][jn_], 0, 0, 0);         \
    __builtin_amdgcn_s_setprio(0);

__global__ __launch_bounds__(512, 2)
void gemm_qkv(const ushort* __restrict__ A, const ushort* __restrict__ B,
              ushort* __restrict__ C, const float2* __restrict__ tab) {
    __shared__ __align__(16) ushort pool[65536];   // 128 KiB

    // bijective XCD remap: each XCD gets 2 full A-stripes (by pairs) x 12 bx
    const int orig = blockIdx.y * gridDim.x + blockIdx.x;   // 0..191
    const int xcd  = orig & 7;
    const int ixd  = orig >> 3;                             // 0..23
    const int by   = xcd * 2 + (ixd / 12);
    const int bx   = ixd % 12;
    const int m0   = by * 256;
    const int n0   = bx * 256;

    const int tid  = threadIdx.x;
    const int lane = tid & 63;
    const int w    = tid >> 6;
    const int l16  = lane & 15;
    const int quad = lane >> 4;
    const int wm   = (w >> 2) * 128;    // 2 wave-rows
    const int wn   = (w & 3) * 64;      // 4 wave-cols
    // read-side swizzled chunk offset (row&7 == l16&7 for all frag reads)
    const int chq  = (quad ^ ((l16 & 3) ^ ((l16 & 4) >> 1))) << 3;
    // staging coords: thread covers one 16B chunk per issue
    const int srow = tid >> 2;          // 0..127
    const int ssc  = (tid & 3) ^ ((srow & 3) ^ ((srow & 4) >> 1));

    // hoisted staging bases (pre-swizzled global source)
    const ushort* gA = A + (size_t)(m0 + srow) * DMODEL + ssc * 8;
    const ushort* gB = B + (size_t)(n0 + srow) * DMODEL + ssc * 8;

    auto stageA = [&](int tt, int ks) {
        const int off = tt * 64 + ks * 32;
        const int lb  = ((tt & 1) << 15) + (ks << 13);
        load16_lds(gA + off,                &pool[lb + tid * 8]);
        load16_lds(gA + 128 * DMODEL + off, &pool[lb + 4096 + tid * 8]);
    };
    auto stageB = [&](int tt, int ks) {
        const int off = tt * 64 + ks * 32;
        const int lb  = ((tt & 1) << 15) + 16384 + (ks << 13);
        load16_lds(gB + off,                &pool[lb + tid * 8]);
        load16_lds(gB + 128 * DMODEL + off, &pool[lb + 4096 + tid * 8]);
    };

    // prologue: AB(0,0), AB(0,1), AB(1,0)  [12 loads]
    stageA(0, 0); stageB(0, 0);
    stageA(0, 1); stageB(0, 1);
    stageA(1, 0); stageB(1, 0);

    f32x4 acc[8][4];
    #pragma unroll
    for (int i = 0; i < 8; i++)
        #pragma unroll
        for (int j = 0; j < 4; j++) acc[i][j] = (f32x4){0.f, 0.f, 0.f, 0.f};

    asm volatile("s_waitcnt vmcnt(4)" ::: "memory");  // AB(0,0..1) landed
    __builtin_amdgcn_s_barrier();

    bf16x8 al[4], ah[4], bc[4], bn[4];

    // pre-loop: operands of phase (0, ks0)
    { const ushort* p = pool + (wm + l16) * 32 + chq;           RD4(al, p); }
    { const ushort* q = pool + 16384 + (wn + l16) * 32 + chq;   RD4(bc, q); }

    #pragma unroll 1
    for (int t = 0; t < 16; t++) {
        const int buf  = (t & 1) << 15;
        const int bufn = buf ^ 32768;
        // ---------- P0: MFMA (t,ks0); prefetch (t,ks1)
        if (t <= 14) { stageA(t + 1, 1); stageB(t + 1, 1); }
        { const ushort* p = pool + buf + (wm + 64 + l16) * 32 + chq;
          RD4(ah, p); }                               // A-hi (t,ks0)
        MFMA_G(al, bc, 0);                            // acc[0..3]
        { const ushort* p = pool + buf + 8192 + (wm + l16) * 32 + chq;
          RD4(al, p);                                 // A-lo (t,ks1)
          const ushort* q = pool + buf + 16384 + 8192 + (wn + l16) * 32 + chq;
          RD4(bn, q); }                               // B    (t,ks1)
        MFMA_G(ah, bc, 4);                            // acc[4..7]
        if (t <= 14) { asm volatile("s_waitcnt vmcnt(4)" ::: "memory"); }
        QKV_BARRIER();
        // ---------- P1: MFMA (t,ks1); prefetch (t+1,ks0)
        if (t <= 13) { stageA(t + 2, 0); stageB(t + 2, 0); }
        { const ushort* p = pool + buf + 8192 + (wm + 64 + l16) * 32 + chq;
          RD4(ah, p); }                               // A-hi (t,ks1)
        MFMA_G(al, bn, 0);
        if (t <= 14) {
            const ushort* p = pool + bufn + (wm + l16) * 32 + chq;
            RD4(al, p);                               // A-lo (t+1,ks0)
            const ushort* q = pool + bufn + 16384 + (wn + l16) * 32 + chq;
            RD4(bc, q);                               // B    (t+1,ks0)
        }
        MFMA_G(ah, bn, 4);
        if (t <= 13)      { asm volatile("s_waitcnt vmcnt(4)" ::: "memory"); }
        else if (t == 14) { asm volatile("s_waitcnt vmcnt(0)" ::: "memory"); }
        QKV_BARRIER();
    }

    const int nbase  = n0 + wn;
    const int tensor = nbase >> 10;        // wave-uniform (block-uniform)
    const int hh     = (nbase & 1023) >> 6;
    if (tensor < 2) {
        // ---- q/k epilogue with fused RoPE ----
        ushort* Dt = C + (size_t)tensor * ((size_t)MROWS * DMODEL);
        #pragma unroll
        for (int i = 0; i < 8; i++)
            #pragma unroll
            for (int r = 0; r < 4; r++) {
                const int m  = m0 + wm + i * 16 + quad * 4 + r;
                const int bb = m >> 11;
                const int ss = m & (SEQ - 1);
                const float2* trow = tab + ss * 32;
                #pragma unroll
                for (int j = 0; j < 4; j++) {
                    const int f = j * 16 + l16;          // dh 0..63
                    const float2 cs = trow[f >> 1];
                    const float val = acc[i][j][r];
                    const float prt = __shfl_xor(val, 1, 64);
                    const float out = (f & 1) ? (prt * cs.y + val * cs.x)
                                              : (val * cs.x - prt * cs.y);
                    Dt[(((size_t)(bb * NHEAD + hh)) * SEQ + ss) * DHEAD + f] =
                        bf16u(out);
                }
            }
    } else {
        // ---- V^T epilogue: wave-private swizzled LDS transpose ----
        // pool free: each wave's MFMAs consumed its ds_reads pre-barrier
        ushort* Tw = pool + w * 8192;   // 16 KB per wave
        #pragma unroll
        for (int i = 0; i < 8; i++)
            #pragma unroll
            for (int j = 0; j < 4; j++) {
                const int f  = j * 16 + l16;
                const int sx = (f & 7) << 3;
                #pragma unroll
                for (int r = 0; r < 4; r += 2) {
                    const int ml = i * 16 + quad * 4 + r;
                    ushort2 pk;
                    pk.x = bf16u(acc[i][j][r]);
                    pk.y = bf16u(acc[i][j][r + 1]);
                    *reinterpret_cast<ushort2*>(&Tw[f * 128 + (ml ^ sx)]) = pk;
                }
            }
        asm volatile("s_waitcnt lgkmcnt(0)" ::: "memory");
        ushort* Dv = C + 2 * ((size_t)MROWS * DMODEL);
        const int c  = lane & 15;        // m-chunk (8 elems)
        const int fb = lane >> 4;        // f sub-row 0..3
        #pragma unroll
        for (int rr = 0; rr < 16; rr++) {
            const int fl = rr * 4 + fb;
            const uint4 v = *reinterpret_cast<const uint4*>(
                &Tw[fl * 128 + ((c << 3) ^ ((fl & 7) << 3))]);
            *reinterpret_cast<uint4*>(
                &Dv[(size_t)(hh * 64 + fl) * MROWS + m0 + wm + (c << 3)]) = v;
        }
    }
}

// ---------------------------------------------------------------------------
// Output GEMM, 64x128 tile, double-buffered. A in [b,h,s,dh], f32 out.
// ---------------------------------------------------------------------------
__global__ __launch_bounds__(256)
void gemm_out64(const ushort* __restrict__ A, const ushort* __restrict__ B,
                float* __restrict__ C) {
    __shared__ __align__(16) ushort pool[12288];   // As[2][2048] Bs[2][4096]
    ushort* As = pool;
    ushort* Bs = pool + 4096;
    const int tid  = threadIdx.x;
    const int m0   = blockIdx.y * 64;
    const int n0   = blockIdx.x * 128;
    const int lane = tid & 63;
    const int w    = tid >> 6;
    const int l16  = lane & 15;
    const int quad = lane >> 4;
    const int wm   = (w >> 1) * 32;
    const int wn   = (w & 1) * 64;
    const int srow = tid >> 2;        // 0..63
    const int scol = (tid & 3) * 8;

    // A gather address (k -> (h,dh)) for row srow
    const int am  = m0 + srow;
    const int abb = am >> 11;
    const int ass = am & (SEQ - 1);
    const size_t abase = ((size_t)(abb * NHEAD)) * SEQ * DHEAD + (size_t)ass * DHEAD;

    f32x4 acc[2][4];
    #pragma unroll
    for (int i = 0; i < 2; i++)
        #pragma unroll
        for (int j = 0; j < 4; j++) acc[i][j] = (f32x4){0.f, 0.f, 0.f, 0.f};

    // prologue: K-tile 0 -> buffer 0
    {
        const int h = scol >> 6, dh = scol & 63;
        load16_lds(A + abase + (size_t)h * SEQ * DHEAD + dh, &As[srow * 32 + scol]);
        #pragma unroll
        for (int half = 0; half < 2; half++) {
            const int row = srow + half * 64;
            load16_lds(B + (size_t)(n0 + row) * DMODEL + scol, &Bs[row * 32 + scol]);
        }
    }

    for (int t = 0; t < 32; t++) {
        const int bf = t & 1;
        __syncthreads();
        if (t + 1 < 32) {
            const int k0 = (t + 1) * 32;
            const int kk = k0 + scol;
            const int h = kk >> 6, dh = kk & 63;
            load16_lds(A + abase + (size_t)h * SEQ * DHEAD + dh,
                       &As[(bf ^ 1) * 2048 + srow * 32 + scol]);
            #pragma unroll
            for (int half = 0; half < 2; half++) {
                const int row = srow + half * 64;
                load16_lds(B + (size_t)(n0 + row) * DMODEL + k0 + scol,
                           &Bs[(bf ^ 1) * 4096 + row * 32 + scol]);
            }
        }
        const int oa = bf * 2048, ob_ = bf * 4096;
        bf16x8 af[2], bfr[4];
        #pragma unroll
        for (int s = 0; s < 2; s++)
            af[s] = *reinterpret_cast<const bf16x8*>(
                &As[oa + (wm + s * 16 + l16) * 32 + quad * 8]);
        #pragma unroll
        for (int s = 0; s < 4; s++)
            bfr[s] = *reinterpret_cast<const bf16x8*>(
                &Bs[ob_ + (wn + s * 16 + l16) * 32 + quad * 8]);
        #pragma unroll
        for (int i = 0; i < 2; i++)
            #pragma unroll
            for (int j = 0; j < 4; j++)
                acc[i][j] = __builtin_amdgcn_mfma_f32_16x16x32_bf16(
                    af[i], bfr[j], acc[i][j], 0, 0, 0);
    }
    #pragma unroll
    for (int i = 0; i < 2; i++)
        #pragma unroll
        for (int r = 0; r < 4; r++) {
            const int m = m0 + wm + i * 16 + quad * 4 + r;
            #pragma unroll
            for (int j = 0; j < 4; j++)
                C[(size_t)m * DMODEL + n0 + wn + j * 16 + l16] = acc[i][j][r];
        }
}

// ---------------------------------------------------------------------------
// MFMA flash attention v6 (unchanged): single-barrier async-DMA
// double-buffer + max-free exp2-domain softmax.
// ---------------------------------------------------------------------------
__global__ __launch_bounds__(256)
void attn_mfma6(const ushort* __restrict__ qb, const ushort* __restrict__ kb,
                const ushort* __restrict__ vtg, ushort* __restrict__ ob) {
    __shared__ __align__(16) ushort Ks[2][4096];
    __shared__ __align__(16) ushort Vs[2][4096];
    __shared__ ushort Pb[4][16][72];

    const int bh   = blockIdx.x;
    const int b    = bh >> 4;
    const int h    = bh & 15;
    const int qt   = (gridDim.y - 1) - blockIdx.y;
    const int tid  = threadIdx.x;
    const int w    = tid >> 6;
    const int lane = tid & 63;
    const int l16  = lane & 15;
    const int quad = lane >> 4;
    const size_t base = (size_t)bh * SEQ * DHEAD;

    const int qlo = qt * 64 + w * 16;

    const float SC = 0.125f * 1.44269504088896f;
    bf16x8 qa[2];
    {
        const size_t qo = base + (size_t)(qlo + l16) * DHEAD + quad * 8;
        qa[0] = *reinterpret_cast<const bf16x8*>(qb + qo);
        qa[1] = *reinterpret_cast<const bf16x8*>(qb + qo + 32);
        #pragma unroll
        for (int j = 0; j < 8; j++) {
            qa[0][j] = (__bf16)(SC * (float)qa[0][j]);
            qa[1][j] = (__bf16)(SC * (float)qa[1][j]);
        }
    }

    f32x4 oacc[4];
    #pragma unroll
    for (int s = 0; s < 4; s++) oacc[s] = (f32x4){0.f, 0.f, 0.f, 0.f};
    float l_ = 0.f;

    const int c0 = tid,        r0 = c0 >> 3, g0 = (c0 & 7) ^ (r0 & 7);
    const int c1 = 256 + tid,  r1 = c1 >> 3, g1 = (c1 & 7) ^ (r1 & 7);
    const ushort* kg0 = kb + base + (size_t)r0 * DHEAD + g0 * 8;
    const ushort* kg1 = kb + base + (size_t)r1 * DHEAD + g1 * 8;
    const ushort* vg0 = vtg + (size_t)(h * DHEAD + r0) * MROWS + b * SEQ + g0 * 8;
    const ushort* vg1 = vtg + (size_t)(h * DHEAD + r1) * MROWS + b * SEQ + g1 * 8;

    int koff[2][4];
    #pragma unroll
    for (int half = 0; half < 2; half++)
        #pragma unroll
        for (int sub = 0; sub < 4; sub++)
            koff[half][sub] = (sub * 16 + l16) * 64 +
                              (((half * 4 + quad) ^ (l16 & 7)) * 8);

    load16_lds(kg0, &Ks[0][c0 * 8]);
    load16_lds(kg1, &Ks[0][c1 * 8]);
    load16_lds(vg0, &Vs[0][c0 * 8]);
    load16_lds(vg1, &Vs[0][c1 * 8]);

    const int T = qt + 1;
    for (int t = 0; t < T; t++) {
        const int bf = t & 1;
        __syncthreads();
        if (t + 1 < T) {
            const size_t ko = (size_t)(t + 1) * 64 * DHEAD;
            const int    vo = (t + 1) * 64;
            load16_lds(kg0 + ko, &Ks[bf ^ 1][c0 * 8]);
            load16_lds(kg1 + ko, &Ks[bf ^ 1][c1 * 8]);
            load16_lds(vg0 + vo, &Vs[bf ^ 1][c0 * 8]);
            load16_lds(vg1 + vo, &Vs[bf ^ 1][c1 * 8]);
        }

        const bool diag = (t == qt);
        const int nsub = diag ? (w + 1) : 4;
        const int nhv  = diag ? ((w >> 1) + 1) : 2;

        f32x4 sacc[4];
        #pragma unroll
        for (int s = 0; s < 4; s++) sacc[s] = (f32x4){0.f, 0.f, 0.f, 0.f};
        #pragma unroll
        for (int half = 0; half < 2; half++)
            #pragma unroll
            for (int sub = 0; sub < 4; sub++)
                if (sub < nsub) {
                    const bf16x8 kf = *reinterpret_cast<const bf16x8*>(
                        &Ks[bf][koff[half][sub]]);
                    sacc[sub] = __builtin_amdgcn_mfma_f32_16x16x32_bf16(
                        kf, qa[half], sacc[sub], 0, 0, 0);
                }

        float ev[4][4];
        if (diag) {
            const int thr = qlo + l16 - t * 64;
            #pragma unroll
            for (int sub = 0; sub < 4; sub++)
                #pragma unroll
                for (int r = 0; r < 4; r++) {
                    const float e = (sub * 16 + quad * 4 + r <= thr)
                                        ? exp2f(sacc[sub][r]) : 0.f;
                    ev[sub][r] = e;
                    l_ += e;
                }
        } else {
            #pragma unroll
            for (int sub = 0; sub < 4; sub++)
                #pragma unroll
                for (int r = 0; r < 4; r++) {
                    const float e = exp2f(sacc[sub][r]);
                    ev[sub][r] = e;
                    l_ += e;
                }
        }

        #pragma unroll
        for (int sub = 0; sub < 4; sub++) {
            ushort4 pk;
            pk.x = bf16u(ev[sub][0]); pk.y = bf16u(ev[sub][1]);
            pk.z = bf16u(ev[sub][2]); pk.w = bf16u(ev[sub][3]);
            *reinterpret_cast<ushort4*>(&Pb[w][l16][sub * 16 + quad * 4]) = pk;
        }
        bf16x8 pa[2];
        pa[0] = *reinterpret_cast<const bf16x8*>(&Pb[w][l16][quad * 8]);
        pa[1] = *reinterpret_cast<const bf16x8*>(&Pb[w][l16][32 + quad * 8]);

        #pragma unroll
        for (int hk = 0; hk < 2; hk++) {
            if (hk >= nhv) break;
            #pragma unroll
            for (int sf = 0; sf < 4; sf++) {
                const bf16x8 vf = *reinterpret_cast<const bf16x8*>(
                    &Vs[bf][koff[hk][sf]]);
                oacc[sf] = __builtin_amdgcn_mfma_f32_16x16x32_bf16(
                    pa[hk], vf, oacc[sf], 0, 0, 0);
            }
        }
    }

    l_ += __shfl_xor(l_, 16, 64);
    l_ += __shfl_xor(l_, 32, 64);
    float inv[4];
    #pragma unroll
    for (int r = 0; r < 4; r++) inv[r] = 1.f / __shfl(l_, quad * 4 + r, 64);
    #pragma unroll
    for (int sub = 0; sub < 4; sub++)
        #pragma unroll
        for (int r = 0; r < 4; r++) {
            const int q = qlo + quad * 4 + r;
            ob[base + (size_t)q * DHEAD + sub * 16 + l16] =
                bf16u(oacc[sub][r] * inv[r]);
        }
}

// ---------------------------------------------------------------------------
extern "C" void kernel_launch(void* const* d_in, const int* in_sizes, int n_in,
                              void* d_out, int out_size, void* d_ws, size_t ws_size,
                              hipStream_t stream) {
    const float* x  = (const float*)d_in[0];
    const float* Wq = (const float*)d_in[1];
    const float* Wk = (const float*)d_in[2];
    const float* Wv = (const float*)d_in[3];
    const float* Wo = (const float*)d_in[4];
    const int* pos = (const int*)d_in[5];

    const size_t TEN = (size_t)MROWS * DMODEL;   // 4M elements
    const size_t WEL = (size_t)DMODEL * DMODEL;  // 1M elements
    ushort* xb   = (ushort*)d_ws;      // 8 MB
    ushort* Wqkv = xb + TEN;           // 8 MB (Wq,Wk,Wv,Wo contiguous)
    ushort* Wob  = Wqkv + 3 * WEL;
    ushort* qb   = Wob + WEL;          // 8 MB each; kb, vtb contiguous
    ushort* kb   = qb + TEN;
    ushort* vtb  = kb + TEN;           // V^T [1024][4096]
    ushort* ob   = vtb + TEN;
    float2* tab  = (float2*)(ob + TEN);  // 512 KB rope table

    dim3 blk(256);
    rope_tab<<<(SEQ * 32) / 256, blk, 0, stream>>>(pos, tab);
    cast_f32_bf16<<<TEN / (8 * 256), blk, 0, stream>>>(x, xb, (int)TEN);
    dim3 gcw(WEL / (8 * 256), 4);
    cast_w4<<<gcw, blk, 0, stream>>>(Wq, Wk, Wv, Wo, Wqkv);

    dim3 gqkv(3 * DMODEL / 256, MROWS / 256);   // (12, 16) = 192 blocks
    gemm_qkv<<<gqkv, dim3(512), 0, stream>>>(xb, Wqkv, qb, tab);

    dim3 gattn(BATCH * NHEAD, SEQ / 64);        // (32, 32)
    attn_mfma6<<<gattn, blk, 0, stream>>>(qb, kb, vtb, ob);

    dim3 gout(DMODEL / 128, MROWS / 64);        // (8, 64)
    gemm_out64<<<gout, blk, 0, stream>>>(ob, Wob, (float*)d_out);
}